// Round 4
// baseline (58.413 us; speedup 1.0000x reference)
//
#include <hip/hip_runtime.h>

#define NN 2048
#define BB 4
#define IN_F 128
#define OUT_F 64
#define NEG_INF -9000000000000000.0f

typedef __attribute__((ext_vector_type(8))) short short8;
typedef __attribute__((ext_vector_type(4))) float f32x4;
typedef __attribute__((ext_vector_type(4))) int i32x4;

__device__ __forceinline__ ushort f2bf(float f) {
  uint u = __float_as_uint(f);
  uint r = (u + 0x7fffu + ((u >> 16) & 1u)) >> 16;   // RNE, finite values
  return (ushort)r;
}

// Kernel 1: 256 thr = 4 waves, 1 row per wave.
// wh[o] = h[row] . W[:,o] (f32) -> Whbf (bf16 row-major);
// el[row] = wh . a_l, er[row] = wh . a_r (wave reduce).
__global__ __launch_bounds__(256) void wh_el_er_kernel(
    const float* __restrict__ h, const float* __restrict__ W,
    const float* __restrict__ a, ushort* __restrict__ Whbf,
    float* __restrict__ el, float* __restrict__ er) {
  int row = blockIdx.x * 4 + (threadIdx.x >> 6);   // b*NN + n
  int o = threadIdx.x & 63;
  const float* hr = h + (size_t)row * IN_F;
  float wh = 0.f;
  #pragma unroll 8
  for (int f = 0; f < IN_F; ++f) wh += hr[f] * W[f * OUT_F + o];
  Whbf[(size_t)row * OUT_F + o] = f2bf(wh);
  float vl = wh * a[o];
  float vr = wh * a[OUT_F + o];
  #pragma unroll
  for (int d = 32; d > 0; d >>= 1) {
    vl += __shfl_down(vl, d);
    vr += __shfl_down(vr, d);
  }
  if (o == 0) { el[row] = vl; er[row] = vr; }
}

// Kernel 1b: WhbfT[b][o][j] = Whbf[b][j][o] (bf16 transpose, 64x2048/batch).
__global__ __launch_bounds__(256) void transpose_kernel(
    const ushort* __restrict__ Whbf, ushort* __restrict__ WhbfT) {
  __shared__ uint tile[64][65];
  int b = blockIdx.x >> 5;          // /32
  int j0 = (blockIdx.x & 31) << 6;  // *64
  int t = threadIdx.x;
  int o = t & 63, jg = t >> 6;      // 4 j-groups of 16
  #pragma unroll
  for (int m = 0; m < 16; ++m) {
    int jj = jg * 16 + m;
    tile[jj][o] = (uint)Whbf[((size_t)(b * NN + j0 + jj)) * OUT_F + o];
  }
  __syncthreads();
  int oo = t >> 2, grp = t & 3;     // 64 o x 4 chunks of 16 j
  uint out[8];
  #pragma unroll
  for (int m = 0; m < 16; m += 2) {
    uint u0 = tile[grp * 16 + m][oo];
    uint u1 = tile[grp * 16 + m + 1][oo];
    out[m >> 1] = u0 | (u1 << 16);
  }
  uint4* dst = (uint4*)(WhbfT + ((size_t)(b * OUT_F + oo)) * NN + j0 + grp * 16);
  dst[0] = *(uint4*)&out[0];
  dst[1] = *(uint4*)&out[4];
}

// Kernel 2: block = 16 rows of one batch, 1024 threads (16 waves).
// Phase 1: wave w -> row i0+w: register softmax; attention out via
//          NONTEMPORAL f32x4 stores (keeps adj L3-resident), p -> bf16
//          XOR-swizzled LDS.
// Phase 2: h_prime[16][64] = p @ Wh via mfma_f32_16x16x32_bf16.
//          wave = (ntile = w&3, kq = w>>2); 16 MFMAs per wave over k-quarter.
//          Cross-kq reduce reuses pbuf (dead after MFMA barrier), padded 17.
__global__ __launch_bounds__(1024, 2) void attn_kernel(
    const int* __restrict__ adj, const ushort* __restrict__ WhbfT,
    const float* __restrict__ el, const float* __restrict__ er,
    float* __restrict__ attn_out, float* __restrict__ hprime) {
  __shared__ __align__(16) char pbuf[16 * 4096];  // 64 KB: p bf16 [16][2048]

  int blk = blockIdx.x;
  int b = blk >> 7;             // /128
  int i0 = (blk & 127) << 4;    // *16
  int tid = threadIdx.x;
  int wave = tid >> 6, lane = tid & 63;

  // ---- Phase 1: masked softmax, 1 row per wave ----
  {
    int r = wave;
    int i = i0 + r;
    float eli = el[(size_t)b * NN + i];
    const i32x4* arow4 = (const i32x4*)(adj + ((size_t)(b * NN + i)) * NN);
    const f32x4* er4 = (const f32x4*)(er + (size_t)b * NN);

    float pv[8][4];
    float mx = NEG_INF;
    #pragma unroll
    for (int it = 0; it < 8; ++it) {
      i32x4 av = arow4[lane + 64 * it];
      f32x4 ev = er4[lane + 64 * it];
      float e0 = eli + ev.x; e0 = e0 > 0.f ? e0 : 0.2f * e0;
      float e1 = eli + ev.y; e1 = e1 > 0.f ? e1 : 0.2f * e1;
      float e2 = eli + ev.z; e2 = e2 > 0.f ? e2 : 0.2f * e2;
      float e3 = eli + ev.w; e3 = e3 > 0.f ? e3 : 0.2f * e3;
      pv[it][0] = av.x > 0 ? e0 : NEG_INF;
      pv[it][1] = av.y > 0 ? e1 : NEG_INF;
      pv[it][2] = av.z > 0 ? e2 : NEG_INF;
      pv[it][3] = av.w > 0 ? e3 : NEG_INF;
      mx = fmaxf(mx, fmaxf(fmaxf(pv[it][0], pv[it][1]), fmaxf(pv[it][2], pv[it][3])));
    }
    #pragma unroll
    for (int d = 32; d > 0; d >>= 1) mx = fmaxf(mx, __shfl_xor(mx, d));

    float s = 0.f;
    #pragma unroll
    for (int it = 0; it < 8; ++it) {
      #pragma unroll
      for (int k = 0; k < 4; ++k) {
        float pe = __expf(pv[it][k] - mx);   // all-masked row -> exp(0)=1 each
        pv[it][k] = pe;
        s += pe;
      }
    }
    #pragma unroll
    for (int d = 32; d > 0; d >>= 1) s += __shfl_xor(s, d);
    float inv = 1.f / s;

    f32x4* orow4 = (f32x4*)(attn_out + ((size_t)(b * NN + i)) * NN);
    char* prow = pbuf + r * 4096;
    int sw = (r & 7) << 4;
    #pragma unroll
    for (int it = 0; it < 8; ++it) {
      f32x4 v;
      v.x = pv[it][0] * inv; v.y = pv[it][1] * inv;
      v.z = pv[it][2] * inv; v.w = pv[it][3] * inv;
      __builtin_nontemporal_store(v, &orow4[lane + 64 * it]);   // attention f32
      uint lo = (uint)f2bf(v.x) | ((uint)f2bf(v.y) << 16);
      uint hi = (uint)f2bf(v.z) | ((uint)f2bf(v.w) << 16);
      uint2 w2; w2.x = lo; w2.y = hi;
      *(uint2*)(prow + (((lane + 64 * it) * 8) ^ sw)) = w2;     // swizzled bf16
    }
  }
  __syncthreads();

  // ---- Phase 2: MFMA p @ Wh; wave = (ntile, k-quarter) ----
  int ntile = wave & 3, kq = wave >> 2;
  int o0 = ntile * 16;
  int lo16 = lane & 15, hi4 = lane >> 4;

  const char* prowA = pbuf + lo16 * 4096;
  int swA = (lo16 & 7) << 4;
  const ushort* brow = WhbfT + ((size_t)(b * OUT_F + o0 + lo16)) * NN;

  f32x4 acc = {0.f, 0.f, 0.f, 0.f};
  #pragma unroll 4
  for (int kk = 0; kk < 16; ++kk) {
    int kbase = kq * 512 + kk * 32 + hi4 * 8;
    short8 afrag = *(const short8*)(prowA + ((kbase * 2) ^ swA));
    short8 bfrag = *(const short8*)(brow + kbase);
    acc = __builtin_amdgcn_mfma_f32_16x16x32_bf16(afrag, bfrag, acc, 0, 0, 0);
  }
  __syncthreads();       // all pbuf reads done -> safe to reuse as `red`

  float* red = (float*)pbuf;   // [3][4 ntile][16 row][17] padded
  if (kq > 0) {
    #pragma unroll
    for (int q = 0; q < 4; ++q) {
      int crow = hi4 * 4 + q;
      red[(((kq - 1) * 4 + ntile) * 16 + crow) * 17 + lo16] = acc[q];
    }
  }
  __syncthreads();
  if (kq == 0) {
    #pragma unroll
    for (int q = 0; q < 4; ++q) {
      int crow = hi4 * 4 + q;
      float v = acc[q]
              + red[((0 * 4 + ntile) * 16 + crow) * 17 + lo16]
              + red[((1 * 4 + ntile) * 16 + crow) * 17 + lo16]
              + red[((2 * 4 + ntile) * 16 + crow) * 17 + lo16];
      v = v > 0.f ? v : 0.01f * v;                     // leaky_relu 0.01
      hprime[((size_t)(b * NN + i0 + crow)) * OUT_F + o0 + lo16] = v;
    }
  }
}

extern "C" void kernel_launch(void* const* d_in, const int* in_sizes, int n_in,
                              void* d_out, int out_size, void* d_ws, size_t ws_size,
                              hipStream_t stream) {
  const float* h  = (const float*)d_in[0];
  const int* adj  = (const int*)d_in[1];
  const float* W  = (const float*)d_in[2];
  const float* a  = (const float*)d_in[3];

  float* hprime   = (float*)d_out;                           // B*N*OUT_F
  float* attn_out = (float*)d_out + (size_t)BB * NN * OUT_F; // B*N*N

  // workspace: Whbf bf16 [B*N*64], WhbfT bf16 [B*64*N], el f32, er f32 (~2.1 MB)
  ushort* Whbf  = (ushort*)d_ws;
  ushort* WhbfT = Whbf + (size_t)BB * NN * OUT_F;
  float* el = (float*)(WhbfT + (size_t)BB * OUT_F * NN);
  float* er = el + (size_t)BB * NN;

  hipLaunchKernelGGL(wh_el_er_kernel, dim3(BB * NN / 4), dim3(256), 0, stream,
                     h, W, a, Whbf, el, er);
  hipLaunchKernelGGL(transpose_kernel, dim3(BB * (NN / 64)), dim3(256), 0, stream,
                     Whbf, WhbfT);
  hipLaunchKernelGGL(attn_kernel, dim3(BB * (NN / 16)), dim3(1024), 0, stream,
                     adj, WhbfT, el, er, attn_out, hprime);
}